// Round 2
// 851.394 us; speedup vs baseline: 1.9945x; 1.9945x over previous
//
#include <hip/hip_runtime.h>
#include <stdint.h>

// Top2Gate: N=65536 rows, D=2048 features, K=64 experts, fp32.
// out = [top2_probs (N*K) | entropy (N) | logits (N*K)]  (float32, concat)
//
// MFMA formulation: fp32 = h + m + l (exact 3x bf16 mantissa-truncation
// split). logits = sum of 6 MFMA terms (hH, hM, mH, hL, mM, lH); dropped
// cross terms are <= 2^-24 relative -> logit error ~1e-6, same order as the
// previous (passing) serial-fp32 kernel.
//
// Wave = 32 rows x all 64 experts: 2 row-tiles x 4 expert-tiles of
// mfma_f32_16x16x32_bf16. A and B are loaded with the SAME slot->d mapping
// (d_local = (lane>>4)*8 + e), so correctness is independent of the
// hardware's internal A/B k-ordering. C/D layout (HW-verified):
// col = lane&15, row = (lane>>4)*4 + reg.
// No LDS, no barriers; x streamed exactly once; W (512 KB) is L2-resident.

#define NN 65536
#define DD 2048
#define KK 64

typedef __attribute__((ext_vector_type(8))) short bf16x8;   // 8 bf16 (4 VGPRs)
typedef __attribute__((ext_vector_type(4))) float f32x4;

struct Frag3 { bf16x8 h, m, l; };

union FragU { uint32_t w[4]; bf16x8 v; };

// Split 8 fp32 values (slots 0..7) into three packed bf16x8 fragments.
// Truncation split: x = h + m + l EXACTLY (24 mantissa bits = 3 x 8).
__device__ __forceinline__ Frag3 split3(float4 a, float4 b) {
  float xs[8] = {a.x, a.y, a.z, a.w, b.x, b.y, b.z, b.w};
  uint32_t hu[8], mu[8], lu[8];
#pragma unroll
  for (int e = 0; e < 8; ++e) {
    const uint32_t u = __float_as_uint(xs[e]);
    hu[e] = u & 0xffff0000u;                       // top 8 mantissa bits
    const float r1 = xs[e] - __uint_as_float(hu[e]);   // exact
    mu[e] = __float_as_uint(r1) & 0xffff0000u;     // next 8 bits
    const float r2 = r1 - __uint_as_float(mu[e]);  // exact, bf16-representable
    lu[e] = __float_as_uint(r2);                   // low 16 bits already 0
  }
  FragU H, M, L;
#pragma unroll
  for (int j = 0; j < 4; ++j) {
    H.w[j] = (hu[2 * j] >> 16) | (hu[2 * j + 1] & 0xffff0000u);
    M.w[j] = (mu[2 * j] >> 16) | (mu[2 * j + 1] & 0xffff0000u);
    L.w[j] = (lu[2 * j] >> 16) | (lu[2 * j + 1] & 0xffff0000u);
  }
  Frag3 f;
  f.h = H.v; f.m = M.v; f.l = L.v;
  return f;
}

#define MFMA16 __builtin_amdgcn_mfma_f32_16x16x32_bf16

__global__ __launch_bounds__(256) void top2gate_kernel(
    const float* __restrict__ x, const float* __restrict__ W,
    const float* __restrict__ b, float* __restrict__ out) {
  const int tid = threadIdx.x;
  const int lane = tid & 63;
  const int wave = tid >> 6;       // 0..3
  const int lrow = lane & 15;      // row-in-tile (A) / expert-in-tile (B/C)
  const int lkg = lane >> 4;       // k-group 0..3

  const int rowbase = blockIdx.x * 128 + wave * 32;

  // Per-lane base pointers. Slot e of a fragment = d_local (lkg*8 + e).
  const float* __restrict__ xp0 = x + (size_t)(rowbase + lrow) * DD + lkg * 8;
  const float* __restrict__ xp1 = xp0 + (size_t)16 * DD;
  const float* __restrict__ wp0 = W + (size_t)lrow * DD + lkg * 8;

  f32x4 acc[2][4];
#pragma unroll
  for (int rt = 0; rt < 2; ++rt)
#pragma unroll
    for (int et = 0; et < 4; ++et) acc[rt][et] = (f32x4){0.f, 0.f, 0.f, 0.f};

#pragma unroll 1
  for (int d = 0; d < DD; d += 32) {
    // ---- loads: 4x x (HBM stream), 8x W (L2-resident) ----
    const float4 xa0 = *(const float4*)(xp0 + d);
    const float4 xa1 = *(const float4*)(xp0 + d + 4);
    const float4 xb0 = *(const float4*)(xp1 + d);
    const float4 xb1 = *(const float4*)(xp1 + d + 4);
    float4 wv0[4], wv1[4];
#pragma unroll
    for (int et = 0; et < 4; ++et) {
      const float* wp = wp0 + (size_t)et * 16 * DD + d;
      wv0[et] = *(const float4*)(wp);
      wv1[et] = *(const float4*)(wp + 4);
    }

    const Frag3 a0 = split3(xa0, xa1);   // rows rowbase+0..15
    const Frag3 a1 = split3(xb0, xb1);   // rows rowbase+16..31

#pragma unroll
    for (int et = 0; et < 4; ++et) {
      const Frag3 bb = split3(wv0[et], wv1[et]);  // experts et*16..et*16+15
      // 6 terms per (rt, et): hH + hM + mH + hL + mM + lH
      acc[0][et] = MFMA16(a0.h, bb.h, acc[0][et], 0, 0, 0);
      acc[0][et] = MFMA16(a0.h, bb.m, acc[0][et], 0, 0, 0);
      acc[0][et] = MFMA16(a0.m, bb.h, acc[0][et], 0, 0, 0);
      acc[0][et] = MFMA16(a0.h, bb.l, acc[0][et], 0, 0, 0);
      acc[0][et] = MFMA16(a0.m, bb.m, acc[0][et], 0, 0, 0);
      acc[0][et] = MFMA16(a0.l, bb.h, acc[0][et], 0, 0, 0);

      acc[1][et] = MFMA16(a1.h, bb.h, acc[1][et], 0, 0, 0);
      acc[1][et] = MFMA16(a1.h, bb.m, acc[1][et], 0, 0, 0);
      acc[1][et] = MFMA16(a1.m, bb.h, acc[1][et], 0, 0, 0);
      acc[1][et] = MFMA16(a1.h, bb.l, acc[1][et], 0, 0, 0);
      acc[1][et] = MFMA16(a1.m, bb.m, acc[1][et], 0, 0, 0);
      acc[1][et] = MFMA16(a1.l, bb.h, acc[1][et], 0, 0, 0);
    }
  }

  // ---- epilogue: bias, softmax, top-2, renorm, entropy, stores ----
  float bv[4];
#pragma unroll
  for (int et = 0; et < 4; ++et) bv[et] = b[et * 16 + lrow];

  float* __restrict__ ent_out = out + (size_t)NN * KK;
  float* __restrict__ log_base = out + (size_t)NN * KK + NN;

#pragma unroll
  for (int rt = 0; rt < 2; ++rt) {
#pragma unroll
    for (int j = 0; j < 4; ++j) {
      // This lane's (row, 4 experts): row's 64 logits live across the 16
      // consecutive lanes of this lane's group (same lkg), 4 frags each.
      float v[4];
#pragma unroll
      for (int et = 0; et < 4; ++et) v[et] = acc[rt][et][j] + bv[et];
      const int row = rowbase + rt * 16 + lkg * 4 + j;

      // row max (4-step butterfly within the 16-lane group)
      float mx = fmaxf(fmaxf(v[0], v[1]), fmaxf(v[2], v[3]));
#pragma unroll
      for (int off = 1; off < 16; off <<= 1)
        mx = fmaxf(mx, __shfl_xor(mx, off));

      // softmax denominator
      float s = 0.f;
#pragma unroll
      for (int et = 0; et < 4; ++et) s += __expf(v[et] - mx);
#pragma unroll
      for (int off = 1; off < 16; off <<= 1) s += __shfl_xor(s, off);

      // local top-2 (indices ascending -> strict '>' keeps lowest on ties)
      float v1 = -3.0e38f, v2 = -3.0e38f;
      int i1 = 0, i2 = 0;
#pragma unroll
      for (int et = 0; et < 4; ++et) {
        const float val = v[et];
        const int idx = et * 16 + lrow;
        if (val > v1) {
          v2 = v1; i2 = i1; v1 = val; i1 = idx;
        } else if (val > v2) {
          v2 = val; i2 = idx;
        }
      }
      // cross-lane top-2 merge (butterfly allreduce; tie -> lower index)
#pragma unroll
      for (int off = 1; off < 16; off <<= 1) {
        const float ov1 = __shfl_xor(v1, off);
        const float ov2 = __shfl_xor(v2, off);
        const int oi1 = __shfl_xor(i1, off);
        const int oi2 = __shfl_xor(i2, off);
        const bool ofirst = (ov1 > v1) || (ov1 == v1 && oi1 < i1);
        const float w1 = ofirst ? ov1 : v1;
        const int wi1 = ofirst ? oi1 : i1;
        const float lv = ofirst ? v1 : ov1;   // loser's best
        const int li = ofirst ? i1 : oi1;
        const float ws = ofirst ? ov2 : v2;   // winner's second
        const int wsi = ofirst ? oi2 : i2;
        const bool sec = (lv > ws) || (lv == ws && li < wsi);
        v2 = sec ? lv : ws;
        i2 = sec ? li : wsi;
        v1 = w1;
        i1 = wi1;
      }

      const float p1 = __expf(v1 - mx) / s;
      const float p2 = __expf(v2 - mx) / s;
      const float denom = p1 + p2 + 1e-9f;  // reference's exact renorm eps
      const float t1 = p1 / denom;
      const float t2 = p2 / denom;
      const float ent = -(t1 * __logf(fmaxf(t1, 1e-12f)) +
                          t2 * __logf(fmaxf(t2, 1e-12f)));

      float* __restrict__ pr = out + (size_t)row * KK;
      float* __restrict__ lg = log_base + (size_t)row * KK;
#pragma unroll
      for (int et = 0; et < 4; ++et) {
        const int idx = et * 16 + lrow;
        lg[idx] = v[et];
        pr[idx] = (idx == i1) ? t1 : ((idx == i2) ? t2 : 0.f);
      }
      if (lrow == 0) ent_out[row] = ent;  // lanes 0,16,32,48 -> 4 rows
    }
  }
}

extern "C" void kernel_launch(void* const* d_in, const int* in_sizes, int n_in,
                              void* d_out, int out_size, void* d_ws,
                              size_t ws_size, hipStream_t stream) {
  const float* x = (const float*)d_in[0];
  const float* W = (const float*)d_in[1];
  const float* b = (const float*)d_in[2];
  float* out = (float*)d_out;

  dim3 grid(NN / 128);   // 512 blocks: 4 waves x 32 rows each
  dim3 block(256);
  hipLaunchKernelGGL(top2gate_kernel, grid, block, 0, stream, x, W, b, out);
}

// Round 3
// 841.749 us; speedup vs baseline: 2.0173x; 1.0115x over previous
//
#include <hip/hip_runtime.h>
#include <stdint.h>

// Top2Gate: N=65536 rows, D=2048 features, K=64 experts, fp32.
// out = [top2_probs (N*K) | entropy (N) | logits (N*K)]  (float32, concat)
//
// MFMA formulation: fp32 = h + m + l (exact 3x bf16 mantissa-truncation
// split). logits = sum of 6 MFMA terms (hH, hM, mH, hL, mM, lH).
//
// R3 change: W's split is hoisted out of the hot loop into a prep kernel
// (once per call, ~4 us) writing bf16 W_h/W_m/W_l [K][D] into d_ws (768 KB,
// L2-resident). Main loop keeps only the 2 x-splits/iter; B fragments are
// straight 16B bf16x8 loads. Falls back to in-loop W split if ws_size is
// too small.

#define NN 65536
#define DD 2048
#define KK 64

typedef __attribute__((ext_vector_type(8))) short bf16x8;   // 8 bf16 (4 VGPRs)
typedef __attribute__((ext_vector_type(4))) short shortx4;
typedef __attribute__((ext_vector_type(4))) float f32x4;

struct Frag3 { bf16x8 h, m, l; };

union FragU { uint32_t w[4]; bf16x8 v; };

// Split 8 fp32 values (slots 0..7) into three packed bf16x8 fragments.
// Truncation split: x = h + m + l EXACTLY (24 mantissa bits = 3 x 8).
__device__ __forceinline__ Frag3 split3(float4 a, float4 b) {
  float xs[8] = {a.x, a.y, a.z, a.w, b.x, b.y, b.z, b.w};
  uint32_t hu[8], mu[8], lu[8];
#pragma unroll
  for (int e = 0; e < 8; ++e) {
    const uint32_t u = __float_as_uint(xs[e]);
    hu[e] = u & 0xffff0000u;                       // top 8 mantissa bits
    const float r1 = xs[e] - __uint_as_float(hu[e]);   // exact
    mu[e] = __float_as_uint(r1) & 0xffff0000u;     // next 8 bits
    const float r2 = r1 - __uint_as_float(mu[e]);  // exact, bf16-representable
    lu[e] = __float_as_uint(r2);                   // low 16 bits already 0
  }
  FragU H, M, L;
#pragma unroll
  for (int j = 0; j < 4; ++j) {
    H.w[j] = (hu[2 * j] >> 16) | (hu[2 * j + 1] & 0xffff0000u);
    M.w[j] = (mu[2 * j] >> 16) | (mu[2 * j + 1] & 0xffff0000u);
    L.w[j] = (lu[2 * j] >> 16) | (lu[2 * j + 1] & 0xffff0000u);
  }
  Frag3 f;
  f.h = H.v; f.m = M.v; f.l = L.v;
  return f;
}

#define MFMA16 __builtin_amdgcn_mfma_f32_16x16x32_bf16

// ---- prep: split W [K][D] fp32 -> bf16 W_h/W_m/W_l [K][D] in d_ws ----
__global__ __launch_bounds__(256) void wsplit_kernel(
    const float* __restrict__ W, short* __restrict__ wh,
    short* __restrict__ wm, short* __restrict__ wl) {
  const int i = blockIdx.x * 256 + threadIdx.x;  // 0 .. K*D/4-1
  const float4 wv = *(const float4*)(W + 4 * (size_t)i);
  const float xs[4] = {wv.x, wv.y, wv.z, wv.w};
  shortx4 h, m, l;
#pragma unroll
  for (int e = 0; e < 4; ++e) {
    const uint32_t u = __float_as_uint(xs[e]);
    const uint32_t hu = u & 0xffff0000u;
    const float r1 = xs[e] - __uint_as_float(hu);
    const uint32_t mu = __float_as_uint(r1) & 0xffff0000u;
    const float r2 = r1 - __uint_as_float(mu);
    const uint32_t lu = __float_as_uint(r2);
    h[e] = (short)(hu >> 16);
    m[e] = (short)(mu >> 16);
    l[e] = (short)(lu >> 16);
  }
  *(shortx4*)(wh + 4 * (size_t)i) = h;
  *(shortx4*)(wm + 4 * (size_t)i) = m;
  *(shortx4*)(wl + 4 * (size_t)i) = l;
}

// ---- shared epilogue: bias, softmax, top-2, renorm, entropy, stores ----
__device__ __forceinline__ void epilogue(const f32x4 acc[2][4],
                                         const float* __restrict__ b,
                                         float* __restrict__ out, int rowbase,
                                         int lrow, int lkg) {
  float bv[4];
#pragma unroll
  for (int et = 0; et < 4; ++et) bv[et] = b[et * 16 + lrow];

  float* __restrict__ ent_out = out + (size_t)NN * KK;
  float* __restrict__ log_base = out + (size_t)NN * KK + NN;

#pragma unroll
  for (int rt = 0; rt < 2; ++rt) {
#pragma unroll
    for (int j = 0; j < 4; ++j) {
      float v[4];
#pragma unroll
      for (int et = 0; et < 4; ++et) v[et] = acc[rt][et][j] + bv[et];
      const int row = rowbase + rt * 16 + lkg * 4 + j;

      float mx = fmaxf(fmaxf(v[0], v[1]), fmaxf(v[2], v[3]));
#pragma unroll
      for (int off = 1; off < 16; off <<= 1)
        mx = fmaxf(mx, __shfl_xor(mx, off));

      float s = 0.f;
#pragma unroll
      for (int et = 0; et < 4; ++et) s += __expf(v[et] - mx);
#pragma unroll
      for (int off = 1; off < 16; off <<= 1) s += __shfl_xor(s, off);

      float v1 = -3.0e38f, v2 = -3.0e38f;
      int i1 = 0, i2 = 0;
#pragma unroll
      for (int et = 0; et < 4; ++et) {
        const float val = v[et];
        const int idx = et * 16 + lrow;
        if (val > v1) {
          v2 = v1; i2 = i1; v1 = val; i1 = idx;
        } else if (val > v2) {
          v2 = val; i2 = idx;
        }
      }
#pragma unroll
      for (int off = 1; off < 16; off <<= 1) {
        const float ov1 = __shfl_xor(v1, off);
        const float ov2 = __shfl_xor(v2, off);
        const int oi1 = __shfl_xor(i1, off);
        const int oi2 = __shfl_xor(i2, off);
        const bool ofirst = (ov1 > v1) || (ov1 == v1 && oi1 < i1);
        const float w1 = ofirst ? ov1 : v1;
        const int wi1 = ofirst ? oi1 : i1;
        const float lv = ofirst ? v1 : ov1;
        const int li = ofirst ? i1 : oi1;
        const float ws = ofirst ? ov2 : v2;
        const int wsi = ofirst ? oi2 : i2;
        const bool sec = (lv > ws) || (lv == ws && li < wsi);
        v2 = sec ? lv : ws;
        i2 = sec ? li : wsi;
        v1 = w1;
        i1 = wi1;
      }

      const float p1 = __expf(v1 - mx) / s;
      const float p2 = __expf(v2 - mx) / s;
      const float denom = p1 + p2 + 1e-9f;
      const float t1 = p1 / denom;
      const float t2 = p2 / denom;
      const float ent = -(t1 * __logf(fmaxf(t1, 1e-12f)) +
                          t2 * __logf(fmaxf(t2, 1e-12f)));

      float* __restrict__ pr = out + (size_t)row * KK;
      float* __restrict__ lg = log_base + (size_t)row * KK;
#pragma unroll
      for (int et = 0; et < 4; ++et) {
        const int idx = et * 16 + lrow;
        lg[idx] = v[et];
        pr[idx] = (idx == i1) ? t1 : ((idx == i2) ? t2 : 0.f);
      }
      if (lrow == 0) ent_out[row] = ent;
    }
  }
}

// ---- main kernel, pre-split W path ----
__global__ __launch_bounds__(256) void top2gate_kernel(
    const float* __restrict__ x, const short* __restrict__ wh,
    const short* __restrict__ wm, const short* __restrict__ wl,
    const float* __restrict__ b, float* __restrict__ out) {
  const int tid = threadIdx.x;
  const int lane = tid & 63;
  const int wave = tid >> 6;       // 0..3
  const int lrow = lane & 15;      // row-in-tile (A) / expert-in-tile (B/C)
  const int lkg = lane >> 4;       // k-group 0..3

  const int rowbase = blockIdx.x * 128 + wave * 32;

  const float* __restrict__ xp0 = x + (size_t)(rowbase + lrow) * DD + lkg * 8;
  const float* __restrict__ xp1 = xp0 + (size_t)16 * DD;
  const size_t wbase = (size_t)lrow * DD + lkg * 8;

  f32x4 acc[2][4];
#pragma unroll
  for (int rt = 0; rt < 2; ++rt)
#pragma unroll
    for (int et = 0; et < 4; ++et) acc[rt][et] = (f32x4){0.f, 0.f, 0.f, 0.f};

#pragma unroll 1
  for (int d = 0; d < DD; d += 32) {
    // x: HBM stream (coalesced float4); W frags: L2-resident bf16x8.
    const float4 xa0 = *(const float4*)(xp0 + d);
    const float4 xa1 = *(const float4*)(xp0 + d + 4);
    const float4 xb0 = *(const float4*)(xp1 + d);
    const float4 xb1 = *(const float4*)(xp1 + d + 4);

    bf16x8 bh[4], bm[4], bl[4];
#pragma unroll
    for (int et = 0; et < 4; ++et) {
      const size_t wo = wbase + (size_t)et * 16 * DD + d;
      bh[et] = *(const bf16x8*)(wh + wo);
      bm[et] = *(const bf16x8*)(wm + wo);
      bl[et] = *(const bf16x8*)(wl + wo);
    }

    const Frag3 a0 = split3(xa0, xa1);   // rows rowbase+0..15
    const Frag3 a1 = split3(xb0, xb1);   // rows rowbase+16..31

#pragma unroll
    for (int et = 0; et < 4; ++et) {
      acc[0][et] = MFMA16(a0.h, bh[et], acc[0][et], 0, 0, 0);
      acc[0][et] = MFMA16(a0.h, bm[et], acc[0][et], 0, 0, 0);
      acc[0][et] = MFMA16(a0.m, bh[et], acc[0][et], 0, 0, 0);
      acc[0][et] = MFMA16(a0.h, bl[et], acc[0][et], 0, 0, 0);
      acc[0][et] = MFMA16(a0.m, bm[et], acc[0][et], 0, 0, 0);
      acc[0][et] = MFMA16(a0.l, bh[et], acc[0][et], 0, 0, 0);

      acc[1][et] = MFMA16(a1.h, bh[et], acc[1][et], 0, 0, 0);
      acc[1][et] = MFMA16(a1.h, bm[et], acc[1][et], 0, 0, 0);
      acc[1][et] = MFMA16(a1.m, bh[et], acc[1][et], 0, 0, 0);
      acc[1][et] = MFMA16(a1.h, bl[et], acc[1][et], 0, 0, 0);
      acc[1][et] = MFMA16(a1.m, bm[et], acc[1][et], 0, 0, 0);
      acc[1][et] = MFMA16(a1.l, bh[et], acc[1][et], 0, 0, 0);
    }
  }

  epilogue(acc, b, out, rowbase, lrow, lkg);
}

// ---- fallback (round-2 kernel): in-loop W split, no workspace needed ----
__global__ __launch_bounds__(256) void top2gate_fallback(
    const float* __restrict__ x, const float* __restrict__ W,
    const float* __restrict__ b, float* __restrict__ out) {
  const int tid = threadIdx.x;
  const int lane = tid & 63;
  const int wave = tid >> 6;
  const int lrow = lane & 15;
  const int lkg = lane >> 4;

  const int rowbase = blockIdx.x * 128 + wave * 32;

  const float* __restrict__ xp0 = x + (size_t)(rowbase + lrow) * DD + lkg * 8;
  const float* __restrict__ xp1 = xp0 + (size_t)16 * DD;
  const float* __restrict__ wp0 = W + (size_t)lrow * DD + lkg * 8;

  f32x4 acc[2][4];
#pragma unroll
  for (int rt = 0; rt < 2; ++rt)
#pragma unroll
    for (int et = 0; et < 4; ++et) acc[rt][et] = (f32x4){0.f, 0.f, 0.f, 0.f};

#pragma unroll 1
  for (int d = 0; d < DD; d += 32) {
    const float4 xa0 = *(const float4*)(xp0 + d);
    const float4 xa1 = *(const float4*)(xp0 + d + 4);
    const float4 xb0 = *(const float4*)(xp1 + d);
    const float4 xb1 = *(const float4*)(xp1 + d + 4);
    float4 wv0[4], wv1[4];
#pragma unroll
    for (int et = 0; et < 4; ++et) {
      const float* wp = wp0 + (size_t)et * 16 * DD + d;
      wv0[et] = *(const float4*)(wp);
      wv1[et] = *(const float4*)(wp + 4);
    }

    const Frag3 a0 = split3(xa0, xa1);
    const Frag3 a1 = split3(xb0, xb1);

#pragma unroll
    for (int et = 0; et < 4; ++et) {
      const Frag3 bb = split3(wv0[et], wv1[et]);
      acc[0][et] = MFMA16(a0.h, bb.h, acc[0][et], 0, 0, 0);
      acc[0][et] = MFMA16(a0.h, bb.m, acc[0][et], 0, 0, 0);
      acc[0][et] = MFMA16(a0.m, bb.h, acc[0][et], 0, 0, 0);
      acc[0][et] = MFMA16(a0.h, bb.l, acc[0][et], 0, 0, 0);
      acc[0][et] = MFMA16(a0.m, bb.m, acc[0][et], 0, 0, 0);
      acc[0][et] = MFMA16(a0.l, bb.h, acc[0][et], 0, 0, 0);

      acc[1][et] = MFMA16(a1.h, bb.h, acc[1][et], 0, 0, 0);
      acc[1][et] = MFMA16(a1.h, bb.m, acc[1][et], 0, 0, 0);
      acc[1][et] = MFMA16(a1.m, bb.h, acc[1][et], 0, 0, 0);
      acc[1][et] = MFMA16(a1.h, bb.l, acc[1][et], 0, 0, 0);
      acc[1][et] = MFMA16(a1.m, bb.m, acc[1][et], 0, 0, 0);
      acc[1][et] = MFMA16(a1.l, bb.h, acc[1][et], 0, 0, 0);
    }
  }

  epilogue(acc, b, out, rowbase, lrow, lkg);
}

extern "C" void kernel_launch(void* const* d_in, const int* in_sizes, int n_in,
                              void* d_out, int out_size, void* d_ws,
                              size_t ws_size, hipStream_t stream) {
  const float* x = (const float*)d_in[0];
  const float* W = (const float*)d_in[1];
  const float* b = (const float*)d_in[2];
  float* out = (float*)d_out;

  const size_t ws_needed = (size_t)3 * KK * DD * sizeof(short);  // 768 KB
  if (d_ws != nullptr && ws_size >= ws_needed) {
    short* wh = (short*)d_ws;
    short* wm = wh + (size_t)KK * DD;
    short* wl = wm + (size_t)KK * DD;
    // prep: 64*2048/4 = 32768 threads -> 128 blocks x 256
    hipLaunchKernelGGL(wsplit_kernel, dim3(KK * DD / 4 / 256), dim3(256), 0,
                       stream, W, wh, wm, wl);
    hipLaunchKernelGGL(top2gate_kernel, dim3(NN / 128), dim3(256), 0, stream,
                       x, wh, wm, wl, b, out);
  } else {
    hipLaunchKernelGGL(top2gate_fallback, dim3(NN / 128), dim3(256), 0, stream,
                       x, W, b, out);
  }
}